// Round 4
// baseline (205.103 us; speedup 1.0000x reference)
//
#include <hip/hip_runtime.h>
#include <hip/hip_bf16.h>

typedef __attribute__((ext_vector_type(8))) short bf16x8;
typedef __attribute__((ext_vector_type(4))) float f32x4;

#define DEVINL __device__ __forceinline__

static DEVINL ushort f2b(float f) {
    union { float f; unsigned int u; } v; v.f = f;
    unsigned int u = v.u;
    unsigned int r = (u + 0x7FFFu + ((u >> 16) & 1u)) >> 16;
    return (ushort)r;
}

static DEVINL unsigned int cvtpk(float lo, float hi) {
    unsigned int r;
    asm("v_cvt_pk_bf16_f32 %0, %1, %2" : "=v"(r) : "v"(lo), "v"(hi));
    return r;
}

// async global->LDS, 16B per lane; LDS dest = wave-uniform base + lane*16
static DEVINL void gload_lds16(const ushort* g, ushort* l) {
    __builtin_amdgcn_global_load_lds(
        (const __attribute__((address_space(1))) unsigned int*)g,
        (__attribute__((address_space(3))) unsigned int*)l,
        16, 0, 0);
}

// swizzled ushort offset of 16B chunk c (0..7) in row of a [*][64]-bf16 linear tile
static DEVINL int swz(int row, int c) {
    return row * 64 + (((c ^ (row & 7)) & 7) << 3);
}

// ---------------- cast kernels ----------------
// Wcat[n][k], n in [0,4096): rows 0-1023 = Wq*0.125, 1024-2047 = Wk, 2048-3071 = Wv, 3072-4095 = Wp
__global__ void cast_w_kernel(const float* __restrict__ Wq, const float* __restrict__ Wk,
                              const float* __restrict__ Wv, const float* __restrict__ Wp,
                              ushort* __restrict__ out) {
    int idx = blockIdx.x * blockDim.x + threadIdx.x;   // one float4 per thread
    int col4 = idx & 255;          // 1024/4
    int row  = idx >> 8;           // 0..4095
    int which = row >> 10;
    int r = row & 1023;
    const float* src = (which == 0) ? Wq : (which == 1) ? Wk : (which == 2) ? Wv : Wp;
    float s = (which == 0) ? 0.125f : 1.0f;
    float4 v = ((const float4*)src)[r * 256 + col4];
    ushort4 o;
    o.x = f2b(v.x * s); o.y = f2b(v.y * s); o.z = f2b(v.z * s); o.w = f2b(v.w * s);
    ((ushort4*)out)[idx] = o;
}

__global__ void cast_x_kernel(const float* __restrict__ x, ushort* __restrict__ out) {
    int idx = blockIdx.x * blockDim.x + threadIdx.x;   // one float4 per thread
    float4 v = ((const float4*)x)[idx];
    ushort4 o;
    o.x = f2b(v.x); o.y = f2b(v.y); o.z = f2b(v.z); o.w = f2b(v.w);
    ((ushort4*)out)[idx] = o;
}

// ---------------- m97-style GEMM: C[m][n] = sum_k A[m][k]*B[n][k] (+bias) ----------------
// 128x128 tile, BK=64, linear LDS, global_load_lds width=16, XCD-swizzled 1-D grid.
template<bool BF16_OUT>
__global__ __launch_bounds__(256) void gemm_bt_kernel(const ushort* __restrict__ A,
                                                      const ushort* __restrict__ B,
                                                      void* __restrict__ Cv,
                                                      const float* __restrict__ bias,
                                                      int M, int N, int K, int gx) {
    __shared__ ushort Al[128 * 64];
    __shared__ ushort Bl[128 * 64];
    const int tid = threadIdx.x;

    // bijective XCD swizzle (grid % 8 == 0 guaranteed by launch)
    const int nwg = (int)gridDim.x;
    const int cpx = nwg >> 3;
    const int orig = (int)blockIdx.x;
    const int wgid = (orig & 7) * cpx + (orig >> 3);
    const int bx = wgid % gx, by = wgid / gx;
    const int m0 = by * 128, n0 = bx * 128;

    const int lane = tid & 63, wid = tid >> 6;
    const int wm = (wid >> 1) * 64, wn = (wid & 1) * 64;
    const int lr = lane & 15, lg = lane >> 4;

    f32x4 acc[4][4];
    #pragma unroll
    for (int i = 0; i < 4; ++i)
        #pragma unroll
        for (int j = 0; j < 4; ++j)
            acc[i][j] = (f32x4){0.f, 0.f, 0.f, 0.f};

    // staging: wave wid owns rows [wid*32, wid*32+32) of both tiles; 4 issues of 8 rows each
    const int grow = wid * 32 + (lane >> 3);     // + j*8
    const int gcol = (lane & 7) * 8;
    const ushort* ga = A + (size_t)(m0 + grow) * K + gcol;
    const ushort* gb = B + (size_t)(n0 + grow) * K + gcol;
    ushort* la = &Al[wid * 32 * 64];             // wave-uniform
    ushort* lb = &Bl[wid * 32 * 64];

    const int nkt = K >> 6;
    for (int kt = 0; kt < nkt; ++kt) {
        const int kof = kt * 64;
        __syncthreads();
        #pragma unroll
        for (int j = 0; j < 4; ++j) {
            gload_lds16(ga + (size_t)(j * 8) * K + kof, la + j * 8 * 64);
            gload_lds16(gb + (size_t)(j * 8) * K + kof, lb + j * 8 * 64);
        }
        __syncthreads();   // compiler drains vmcnt(0) here
        #pragma unroll
        for (int kk = 0; kk < 64; kk += 32) {
            bf16x8 af[4], bfr[4];
            #pragma unroll
            for (int mi = 0; mi < 4; ++mi)
                af[mi] = *(const bf16x8*)&Al[(wm + mi * 16 + lr) * 64 + kk + lg * 8];
            #pragma unroll
            for (int ni = 0; ni < 4; ++ni)
                bfr[ni] = *(const bf16x8*)&Bl[(wn + ni * 16 + lr) * 64 + kk + lg * 8];
            #pragma unroll
            for (int mi = 0; mi < 4; ++mi)
                #pragma unroll
                for (int ni = 0; ni < 4; ++ni)
                    acc[mi][ni] = __builtin_amdgcn_mfma_f32_16x16x32_bf16(af[mi], bfr[ni], acc[mi][ni], 0, 0, 0);
        }
    }
    // epilogue: D row = (lane>>4)*4 + r, col = lane&15
    #pragma unroll
    for (int mi = 0; mi < 4; ++mi) {
        #pragma unroll
        for (int r = 0; r < 4; ++r) {
            int gm = m0 + wm + mi * 16 + lg * 4 + r;
            #pragma unroll
            for (int ni = 0; ni < 4; ++ni) {
                int gn = n0 + wn + ni * 16 + lr;
                float val = acc[mi][ni][r];
                if (BF16_OUT) {
                    ((ushort*)Cv)[(size_t)gm * N + gn] = f2b(val);
                } else {
                    ((float*)Cv)[(size_t)gm * N + gn] = val + bias[gn];
                }
            }
        }
    }
}

// ---------------- V transpose: Vt[nv][t] = QKV[t][2048+nv] ----------------
__global__ void transpose_v_kernel(const ushort* __restrict__ QKV, ushort* __restrict__ Vt) {
    __shared__ ushort tile[32][33];
    int t0 = blockIdx.x * 32;
    int n0 = blockIdx.y * 32;
    int tx = threadIdx.x, ty = threadIdx.y; // (32,8)
    #pragma unroll
    for (int i = 0; i < 4; ++i) {
        int row = ty + i * 8;
        tile[row][tx] = QKV[(size_t)(t0 + row) * 3072 + 2048 + n0 + tx];
    }
    __syncthreads();
    #pragma unroll
    for (int i = 0; i < 4; ++i) {
        int row = ty + i * 8;
        Vt[(size_t)(n0 + row) * 8192 + t0 + tx] = tile[tx][row];
    }
}

// ---------------- causal flash attention v3 (swapped QK^T) ----------------
// QKV [8192][3072] bf16 (Q pre-scaled by 0.125), Vt [1024][8192] bf16, O [8192][1024] bf16
// 4 waves x 32 q-rows; KVBLK=64; dbuf K/V; swapped S^T layout; O^T accumulators.
__global__ __launch_bounds__(256, 3) void attn_kernel(const ushort* __restrict__ QKV,
                                                      const ushort* __restrict__ Vt,
                                                      ushort* __restrict__ O) {
    __shared__ ushort Kl[2][64 * 64];
    __shared__ ushort Vl[2][64 * 64];
    __shared__ ushort Pl[4][32 * 64];

    const int bh = blockIdx.x, b = bh >> 4, h = bh & 15;
    const int qb = (int)gridDim.y - 1 - (int)blockIdx.y;   // heavy blocks first
    const int q0 = qb * 128;
    const int tid = threadIdx.x, lane = tid & 63, w = tid >> 6;
    const int lr = lane & 15, lg = lane >> 4;
    const int qw = q0 + w * 32;

    // Q fragments (B-frag for swapped QK^T: lane lr = q row, 8 contiguous d at lg*8)
    bf16x8 qf[2][2];   // [nt][ks]
    {
        const ushort* qp = QKV + (size_t)(b * 2048 + qw + lr) * 3072 + h * 64 + lg * 8;
        qf[0][0] = *(const bf16x8*)qp;
        qf[0][1] = *(const bf16x8*)(qp + 32);
        qf[1][0] = *(const bf16x8*)(qp + (size_t)16 * 3072);
        qf[1][1] = *(const bf16x8*)(qp + (size_t)16 * 3072 + 32);
    }

    // O^T accumulators: o[di][nt], C layout: row d = di*16+lg*4+r, col q = nt*16+lr
    f32x4 o[4][2];
    #pragma unroll
    for (int di = 0; di < 4; ++di)
        #pragma unroll
        for (int nt_ = 0; nt_ < 2; ++nt_)
            o[di][nt_] = (f32x4){0.f, 0.f, 0.f, 0.f};
    float mrow[2] = {-INFINITY, -INFINITY};
    float lrow[2] = {0.f, 0.f};

    const size_t kbase = (size_t)(b * 2048) * 3072 + 1024 + h * 64;
    const size_t vbase = (size_t)(h * 64) * 8192 + (size_t)b * 2048;
    const int srow = tid >> 2, sc = tid & 3;   // 64 rows x 4 threads; chunks sc, sc+4
    const int ss0 = swz(srow, sc), ss1 = swz(srow, sc + 4);
    char* const pw = (char*)&Pl[w][0];

    const int nt = qb * 2 + 2;
    uint4 kr0, kr1, vr0, vr1;

    #define LOADT(t) do {                                                      \
        const int kv0s = (t) * 64;                                             \
        const ushort* kg = QKV + kbase + (size_t)(kv0s + srow) * 3072;         \
        const ushort* vg = Vt + vbase + (size_t)srow * 8192 + kv0s;            \
        kr0 = *(const uint4*)&kg[sc * 8];                                      \
        kr1 = *(const uint4*)&kg[sc * 8 + 32];                                 \
        vr0 = *(const uint4*)&vg[sc * 8];                                      \
        vr1 = *(const uint4*)&vg[sc * 8 + 32];                                 \
    } while (0)

    #define WRITET(bufi) do {                                                  \
        *(uint4*)&Kl[bufi][ss0] = kr0;                                         \
        *(uint4*)&Kl[bufi][ss1] = kr1;                                         \
        *(uint4*)&Vl[bufi][ss0] = vr0;                                         \
        *(uint4*)&Vl[bufi][ss1] = vr1;                                         \
    } while (0)

    LOADT(0);
    WRITET(0);
    __syncthreads();

    for (int t = 0; t < nt; ++t) {
        const int buf = t & 1;
        const int kv0 = t * 64;
        const bool have_next = (t + 1 < nt);
        if (have_next) LOADT(t + 1);     // issue early; LDS write after PV (T14)

        if (kv0 <= qw + 31) {
            // ---- swapped QK^T: S^T[kv][q], s[mi][nt] ----
            f32x4 s[4][2];
            #pragma unroll
            for (int mi = 0; mi < 4; ++mi)
                #pragma unroll
                for (int nt_ = 0; nt_ < 2; ++nt_)
                    s[mi][nt_] = (f32x4){0.f, 0.f, 0.f, 0.f};
            __builtin_amdgcn_s_setprio(1);
            #pragma unroll
            for (int ks = 0; ks < 2; ++ks) {
                #pragma unroll
                for (int mi = 0; mi < 4; ++mi) {
                    bf16x8 kf = *(const bf16x8*)&Kl[buf][swz(mi * 16 + lr, ks * 4 + lg)];
                    s[mi][0] = __builtin_amdgcn_mfma_f32_16x16x32_bf16(kf, qf[0][ks], s[mi][0], 0, 0, 0);
                    s[mi][1] = __builtin_amdgcn_mfma_f32_16x16x32_bf16(kf, qf[1][ks], s[mi][1], 0, 0, 0);
                }
            }
            __builtin_amdgcn_s_setprio(0);

            // ---- online softmax: each lane owns q = qw + nt*16 + lr ----
            #pragma unroll
            for (int nt_ = 0; nt_ < 2; ++nt_) {
                const int qn = qw + nt_ * 16 + lr;
                const bool full = (kv0 + 63 <= qw + nt_ * 16);
                const int kvb = kv0 + lg * 4;
                float v[4][4];
                #pragma unroll
                for (int mi = 0; mi < 4; ++mi)
                    #pragma unroll
                    for (int r = 0; r < 4; ++r) {
                        float x = s[mi][nt_][r];
                        if (!full) x = (kvb + mi * 16 + r <= qn) ? x : -INFINITY;
                        v[mi][r] = x;
                    }
                // tile max (16 local + xor16 + xor32)
                float mx0 = fmaxf(fmaxf(v[0][0], v[0][1]), fmaxf(v[0][2], v[0][3]));
                float mx1 = fmaxf(fmaxf(v[1][0], v[1][1]), fmaxf(v[1][2], v[1][3]));
                float mx2 = fmaxf(fmaxf(v[2][0], v[2][1]), fmaxf(v[2][2], v[2][3]));
                float mx3 = fmaxf(fmaxf(v[3][0], v[3][1]), fmaxf(v[3][2], v[3][3]));
                float pmax = fmaxf(fmaxf(mx0, mx1), fmaxf(mx2, mx3));
                pmax = fmaxf(pmax, __shfl_xor(pmax, 16));
                pmax = fmaxf(pmax, __shfl_xor(pmax, 32));

                const bool defer = __all(pmax <= mrow[nt_] + 8.0f);
                float mn;
                if (defer) {
                    mn = mrow[nt_];
                } else {
                    mn = fmaxf(mrow[nt_], pmax);
                    const float al = __expf(mrow[nt_] - mn);
                    lrow[nt_] *= al;
                    #pragma unroll
                    for (int di = 0; di < 4; ++di)
                        #pragma unroll
                        for (int r = 0; r < 4; ++r)
                            o[di][nt_][r] *= al;
                    mrow[nt_] = mn;
                }
                float p[4][4];
                #pragma unroll
                for (int mi = 0; mi < 4; ++mi)
                    #pragma unroll
                    for (int r = 0; r < 4; ++r)
                        p[mi][r] = __expf(v[mi][r] - mn);
                float rs = ((p[0][0] + p[0][1]) + (p[0][2] + p[0][3]))
                         + ((p[1][0] + p[1][1]) + (p[1][2] + p[1][3]))
                         + ((p[2][0] + p[2][1]) + (p[2][2] + p[2][3]))
                         + ((p[3][0] + p[3][1]) + (p[3][2] + p[3][3]));
                rs += __shfl_xor(rs, 16);
                rs += __shfl_xor(rs, 32);
                lrow[nt_] += rs;

                // pack P[q][kv] pairs -> LDS (wave-private, XOR-swizzled, b64 writes)
                const int rowoff = (nt_ * 16 + lr) * 128;
                const int xr = (lr & 7) << 4;
                #pragma unroll
                for (int mi = 0; mi < 4; ++mi) {
                    uint2 val;
                    val.x = cvtpk(p[mi][0], p[mi][1]);
                    val.y = cvtpk(p[mi][2], p[mi][3]);
                    *(uint2*)(pw + rowoff + ((32 * mi + 8 * lg) ^ xr)) = val;
                }
            }
            asm volatile("s_waitcnt lgkmcnt(0)" ::: "memory");
            __builtin_amdgcn_sched_barrier(0);

            // ---- PV: O^T[d][q] += V^T[d][kv] * P^T[kv][q] ----
            __builtin_amdgcn_s_setprio(1);
            #pragma unroll
            for (int ks = 0; ks < 2; ++ks) {
                bf16x8 pb[2];
                #pragma unroll
                for (int nt_ = 0; nt_ < 2; ++nt_) {
                    const int byteoff = (nt_ * 16 + lr) * 128 + (((64 * ks + 16 * lg)) ^ ((lr & 7) << 4));
                    pb[nt_] = *(const bf16x8*)(pw + byteoff);
                }
                #pragma unroll
                for (int di = 0; di < 4; ++di) {
                    bf16x8 vf = *(const bf16x8*)&Vl[buf][swz(di * 16 + lr, ks * 4 + lg)];
                    o[di][0] = __builtin_amdgcn_mfma_f32_16x16x32_bf16(vf, pb[0], o[di][0], 0, 0, 0);
                    o[di][1] = __builtin_amdgcn_mfma_f32_16x16x32_bf16(vf, pb[1], o[di][1], 0, 0, 0);
                }
            }
            __builtin_amdgcn_s_setprio(0);
        }
        if (have_next) WRITET(buf ^ 1);   // vmcnt wait lands here, hidden under compute
        __syncthreads();
    }
    #undef LOADT
    #undef WRITET

    // ---- epilogue: normalize, transpose O^T -> O via Pl, coalesced stores ----
    #pragma unroll
    for (int nt_ = 0; nt_ < 2; ++nt_) {
        const float inv = 1.0f / lrow[nt_];
        const int rowoff = (nt_ * 16 + lr) * 128;
        const int xr = (lr & 7) << 4;
        #pragma unroll
        for (int di = 0; di < 4; ++di) {
            uint2 val;
            val.x = cvtpk(o[di][nt_][0] * inv, o[di][nt_][1] * inv);
            val.y = cvtpk(o[di][nt_][2] * inv, o[di][nt_][3] * inv);
            *(uint2*)(pw + rowoff + ((32 * di + 8 * lg) ^ xr)) = val;
        }
    }
    asm volatile("s_waitcnt lgkmcnt(0)" ::: "memory");
    __builtin_amdgcn_sched_barrier(0);
    {
        const int row = lane >> 1;          // 0..31
        const int half = lane & 1;
        const int xr2 = (row & 7) << 4;
        ushort* og = O + (size_t)(b * 2048 + qw + row) * 1024 + h * 64 + half * 32;
        #pragma unroll
        for (int c = 0; c < 4; ++c) {
            uint4 val = *(const uint4*)(pw + row * 128 + ((half * 64 + c * 16) ^ xr2));
            *(uint4*)&og[c * 8] = val;
        }
    }
}

// ---------------- launch ----------------
extern "C" void kernel_launch(void* const* d_in, const int* in_sizes, int n_in,
                              void* d_out, int out_size, void* d_ws, size_t ws_size,
                              hipStream_t stream) {
    const float* x  = (const float*)d_in[0];
    const float* Wk = (const float*)d_in[1];
    const float* Wq = (const float*)d_in[2];
    const float* Wv = (const float*)d_in[3];
    const float* Wp = (const float*)d_in[4];
    const float* bp = (const float*)d_in[5];
    float* out = (float*)d_out;

    char* ws = (char*)d_ws;
    ushort* Xb   = (ushort*)(ws);                       // 8192x1024 bf16 = 16 MB
    ushort* Wcat = (ushort*)(ws + 16777216);            // 4096x1024 bf16 = 8 MB
    ushort* QKV  = (ushort*)(ws + 25165824);            // 8192x3072 bf16 = 48 MB
    ushort* Vt   = (ushort*)(ws + 75497472);            // 1024x8192 bf16 = 16 MB
    ushort* Obuf = (ushort*)(ws + 92274688);            // 8192x1024 bf16 = 16 MB

    cast_w_kernel<<<4096, 256, 0, stream>>>(Wq, Wk, Wv, Wp, Wcat);
    cast_x_kernel<<<8192, 256, 0, stream>>>(x, Xb);
    gemm_bt_kernel<true><<<1536, 256, 0, stream>>>(Xb, Wcat, QKV, nullptr, 8192, 3072, 1024, 24);
    transpose_v_kernel<<<dim3(256, 32), dim3(32, 8), 0, stream>>>(QKV, Vt);
    attn_kernel<<<dim3(64, 16), 256, 0, stream>>>(QKV, Vt, Obuf);
    gemm_bt_kernel<false><<<512, 256, 0, stream>>>(Obuf, Wcat + (size_t)3072 * 1024, out, bp, 8192, 1024, 1024, 8);
}

// Round 5
// 185.105 us; speedup vs baseline: 1.1080x; 1.1080x over previous
//
#include <hip/hip_runtime.h>
#include <hip/hip_bf16.h>

typedef __attribute__((ext_vector_type(8))) short bf16x8;
typedef __attribute__((ext_vector_type(4))) float f32x4;

#define DEVINL __device__ __forceinline__

static DEVINL ushort f2b(float f) {
    union { float f; unsigned int u; } v; v.f = f;
    unsigned int u = v.u;
    unsigned int r = (u + 0x7FFFu + ((u >> 16) & 1u)) >> 16;
    return (ushort)r;
}

static DEVINL unsigned int cvtpk(float lo, float hi) {
    unsigned int r;
    asm("v_cvt_pk_bf16_f32 %0, %1, %2" : "=v"(r) : "v"(lo), "v"(hi));
    return r;
}

// async global->LDS, 16B per lane; LDS dest = wave-uniform base + lane*16
static DEVINL void gload_lds16(const ushort* g, ushort* l) {
    __builtin_amdgcn_global_load_lds(
        (const __attribute__((address_space(1))) unsigned int*)g,
        (__attribute__((address_space(3))) unsigned int*)l,
        16, 0, 0);
}

// swizzled ushort offset of 16B chunk c (0..7) in row of a [*][64]-bf16 linear tile
static DEVINL int swz(int row, int c) {
    return row * 64 + (((c ^ (row & 7)) & 7) << 3);
}

// ---------------- cast kernels ----------------
// Wcat[n][k], n in [0,4096): rows 0-1023 = Wq*0.125, 1024-2047 = Wk, 2048-3071 = Wv, 3072-4095 = Wp
__global__ void cast_w_kernel(const float* __restrict__ Wq, const float* __restrict__ Wk,
                              const float* __restrict__ Wv, const float* __restrict__ Wp,
                              ushort* __restrict__ out) {
    int idx = blockIdx.x * blockDim.x + threadIdx.x;   // one float4 per thread
    int col4 = idx & 255;          // 1024/4
    int row  = idx >> 8;           // 0..4095
    int which = row >> 10;
    int r = row & 1023;
    const float* src = (which == 0) ? Wq : (which == 1) ? Wk : (which == 2) ? Wv : Wp;
    float s = (which == 0) ? 0.125f : 1.0f;
    float4 v = ((const float4*)src)[r * 256 + col4];
    ushort4 o;
    o.x = f2b(v.x * s); o.y = f2b(v.y * s); o.z = f2b(v.z * s); o.w = f2b(v.w * s);
    ((ushort4*)out)[idx] = o;
}

__global__ void cast_x_kernel(const float* __restrict__ x, ushort* __restrict__ out) {
    int idx = blockIdx.x * blockDim.x + threadIdx.x;   // one float4 per thread
    float4 v = ((const float4*)x)[idx];
    ushort4 o;
    o.x = f2b(v.x); o.y = f2b(v.y); o.z = f2b(v.z); o.w = f2b(v.w);
    ((ushort4*)out)[idx] = o;
}

// ---------------- m97-style GEMM + both-sides swizzle: C[m][n] = sum_k A[m][k]*B[n][k] ----------------
// 128x128 tile, BK=64, linear LDS via global_load_lds w=16 with PRE-SWIZZLED global source
// (lane loads chunk (lane&7)^(lane>>3)), fragment reads via swz() -> conflict-free.
template<bool BF16_OUT>
__global__ __launch_bounds__(256) void gemm_bt_kernel(const ushort* __restrict__ A,
                                                      const ushort* __restrict__ B,
                                                      void* __restrict__ Cv,
                                                      const float* __restrict__ bias,
                                                      int M, int N, int K, int gx) {
    __shared__ ushort Al[128 * 64];
    __shared__ ushort Bl[128 * 64];
    const int tid = threadIdx.x;

    // bijective XCD swizzle (grid % 8 == 0 guaranteed by launch)
    const int nwg = (int)gridDim.x;
    const int cpx = nwg >> 3;
    const int orig = (int)blockIdx.x;
    const int wgid = (orig & 7) * cpx + (orig >> 3);
    const int bx = wgid % gx, by = wgid / gx;
    const int m0 = by * 128, n0 = bx * 128;

    const int lane = tid & 63, wid = tid >> 6;
    const int wm = (wid >> 1) * 64, wn = (wid & 1) * 64;
    const int lr = lane & 15, lg = lane >> 4;

    f32x4 acc[4][4];
    #pragma unroll
    for (int i = 0; i < 4; ++i)
        #pragma unroll
        for (int j = 0; j < 4; ++j)
            acc[i][j] = (f32x4){0.f, 0.f, 0.f, 0.f};

    // staging: wave wid owns rows [wid*32, wid*32+32); lane -> row wid*32 + (lane>>3) (+j*8),
    // global chunk is XOR-permuted so linear LDS slots hold swizzled content (rule #21)
    const int grow = wid * 32 + (lane >> 3);
    const int gcol = (((lane & 7) ^ (lane >> 3)) & 7) * 8;   // pre-swizzled source chunk
    const ushort* ga = A + (size_t)(m0 + grow) * K + gcol;
    const ushort* gb = B + (size_t)(n0 + grow) * K + gcol;
    ushort* la = &Al[wid * 32 * 64];             // wave-uniform
    ushort* lb = &Bl[wid * 32 * 64];

    const int nkt = K >> 6;
    for (int kt = 0; kt < nkt; ++kt) {
        const int kof = kt * 64;
        __syncthreads();
        #pragma unroll
        for (int j = 0; j < 4; ++j) {
            gload_lds16(ga + (size_t)(j * 8) * K + kof, la + j * 8 * 64);
            gload_lds16(gb + (size_t)(j * 8) * K + kof, lb + j * 8 * 64);
        }
        __syncthreads();   // compiler drains vmcnt(0) here
        #pragma unroll
        for (int kk = 0; kk < 64; kk += 32) {
            bf16x8 af[4], bfr[4];
            #pragma unroll
            for (int mi = 0; mi < 4; ++mi)
                af[mi] = *(const bf16x8*)&Al[swz(wm + mi * 16 + lr, (kk >> 3) + lg)];
            #pragma unroll
            for (int ni = 0; ni < 4; ++ni)
                bfr[ni] = *(const bf16x8*)&Bl[swz(wn + ni * 16 + lr, (kk >> 3) + lg)];
            #pragma unroll
            for (int mi = 0; mi < 4; ++mi)
                #pragma unroll
                for (int ni = 0; ni < 4; ++ni)
                    acc[mi][ni] = __builtin_amdgcn_mfma_f32_16x16x32_bf16(af[mi], bfr[ni], acc[mi][ni], 0, 0, 0);
        }
    }
    // epilogue: D row = (lane>>4)*4 + r, col = lane&15
    #pragma unroll
    for (int mi = 0; mi < 4; ++mi) {
        #pragma unroll
        for (int r = 0; r < 4; ++r) {
            int gm = m0 + wm + mi * 16 + lg * 4 + r;
            #pragma unroll
            for (int ni = 0; ni < 4; ++ni) {
                int gn = n0 + wn + ni * 16 + lr;
                float val = acc[mi][ni][r];
                if (BF16_OUT) {
                    ((ushort*)Cv)[(size_t)gm * N + gn] = f2b(val);
                } else {
                    ((float*)Cv)[(size_t)gm * N + gn] = val + bias[gn];
                }
            }
        }
    }
}

// ---------------- V transpose: Vt[nv][t] = QKV[t][2048+nv] ----------------
__global__ void transpose_v_kernel(const ushort* __restrict__ QKV, ushort* __restrict__ Vt) {
    __shared__ ushort tile[32][33];
    int t0 = blockIdx.x * 32;
    int n0 = blockIdx.y * 32;
    int tx = threadIdx.x, ty = threadIdx.y; // (32,8)
    #pragma unroll
    for (int i = 0; i < 4; ++i) {
        int row = ty + i * 8;
        tile[row][tx] = QKV[(size_t)(t0 + row) * 3072 + 2048 + n0 + tx];
    }
    __syncthreads();
    #pragma unroll
    for (int i = 0; i < 4; ++i) {
        int row = ty + i * 8;
        Vt[(size_t)(n0 + row) * 8192 + t0 + tx] = tile[tx][row];
    }
}

// ---------------- causal flash attention v3 (swapped QK^T) ----------------
// QKV [8192][3072] bf16 (Q pre-scaled by 0.125), Vt [1024][8192] bf16, O [8192][1024] bf16
// 4 waves x 32 q-rows; KVBLK=64; dbuf K/V; swapped S^T layout; O^T accumulators.
__global__ __launch_bounds__(256, 3) void attn_kernel(const ushort* __restrict__ QKV,
                                                      const ushort* __restrict__ Vt,
                                                      ushort* __restrict__ O) {
    __shared__ ushort Kl[2][64 * 64];
    __shared__ ushort Vl[2][64 * 64];
    __shared__ ushort Pl[4][32 * 64];

    const int bh = blockIdx.x, b = bh >> 4, h = bh & 15;
    const int qb = (int)gridDim.y - 1 - (int)blockIdx.y;   // heavy blocks first
    const int q0 = qb * 128;
    const int tid = threadIdx.x, lane = tid & 63, w = tid >> 6;
    const int lr = lane & 15, lg = lane >> 4;
    const int qw = q0 + w * 32;

    // Q fragments (B-frag for swapped QK^T: lane lr = q row, 8 contiguous d at lg*8)
    bf16x8 qf[2][2];   // [nt][ks]
    {
        const ushort* qp = QKV + (size_t)(b * 2048 + qw + lr) * 3072 + h * 64 + lg * 8;
        qf[0][0] = *(const bf16x8*)qp;
        qf[0][1] = *(const bf16x8*)(qp + 32);
        qf[1][0] = *(const bf16x8*)(qp + (size_t)16 * 3072);
        qf[1][1] = *(const bf16x8*)(qp + (size_t)16 * 3072 + 32);
    }

    // O^T accumulators: o[di][nt], C layout: row d = di*16+lg*4+r, col q = nt*16+lr
    f32x4 o[4][2];
    #pragma unroll
    for (int di = 0; di < 4; ++di)
        #pragma unroll
        for (int nt_ = 0; nt_ < 2; ++nt_)
            o[di][nt_] = (f32x4){0.f, 0.f, 0.f, 0.f};
    float mrow[2] = {-INFINITY, -INFINITY};
    float lrow[2] = {0.f, 0.f};

    const size_t kbase = (size_t)(b * 2048) * 3072 + 1024 + h * 64;
    const size_t vbase = (size_t)(h * 64) * 8192 + (size_t)b * 2048;
    const int srow = tid >> 2, sc = tid & 3;   // 64 rows x 4 threads; chunks sc, sc+4
    const int ss0 = swz(srow, sc), ss1 = swz(srow, sc + 4);
    char* const pw = (char*)&Pl[w][0];

    const int nt = qb * 2 + 2;
    uint4 kr0, kr1, vr0, vr1;

    #define LOADT(t) do {                                                      \
        const int kv0s = (t) * 64;                                             \
        const ushort* kg = QKV + kbase + (size_t)(kv0s + srow) * 3072;         \
        const ushort* vg = Vt + vbase + (size_t)srow * 8192 + kv0s;            \
        kr0 = *(const uint4*)&kg[sc * 8];                                      \
        kr1 = *(const uint4*)&kg[sc * 8 + 32];                                 \
        vr0 = *(const uint4*)&vg[sc * 8];                                      \
        vr1 = *(const uint4*)&vg[sc * 8 + 32];                                 \
    } while (0)

    #define WRITET(bufi) do {                                                  \
        *(uint4*)&Kl[bufi][ss0] = kr0;                                         \
        *(uint4*)&Kl[bufi][ss1] = kr1;                                         \
        *(uint4*)&Vl[bufi][ss0] = vr0;                                         \
        *(uint4*)&Vl[bufi][ss1] = vr1;                                         \
    } while (0)

    LOADT(0);
    WRITET(0);
    __syncthreads();

    for (int t = 0; t < nt; ++t) {
        const int buf = t & 1;
        const int kv0 = t * 64;
        const bool have_next = (t + 1 < nt);
        if (have_next) LOADT(t + 1);     // issue early; LDS write after PV (T14)

        if (kv0 <= qw + 31) {
            // ---- swapped QK^T: S^T[kv][q], s[mi][nt] ----
            f32x4 s[4][2];
            #pragma unroll
            for (int mi = 0; mi < 4; ++mi)
                #pragma unroll
                for (int nt_ = 0; nt_ < 2; ++nt_)
                    s[mi][nt_] = (f32x4){0.f, 0.f, 0.f, 0.f};
            __builtin_amdgcn_s_setprio(1);
            #pragma unroll
            for (int ks = 0; ks < 2; ++ks) {
                #pragma unroll
                for (int mi = 0; mi < 4; ++mi) {
                    bf16x8 kf = *(const bf16x8*)&Kl[buf][swz(mi * 16 + lr, ks * 4 + lg)];
                    s[mi][0] = __builtin_amdgcn_mfma_f32_16x16x32_bf16(kf, qf[0][ks], s[mi][0], 0, 0, 0);
                    s[mi][1] = __builtin_amdgcn_mfma_f32_16x16x32_bf16(kf, qf[1][ks], s[mi][1], 0, 0, 0);
                }
            }
            __builtin_amdgcn_s_setprio(0);

            // ---- online softmax: each lane owns q = qw + nt*16 + lr ----
            #pragma unroll
            for (int nt_ = 0; nt_ < 2; ++nt_) {
                const int qn = qw + nt_ * 16 + lr;
                const bool full = (kv0 + 63 <= qw + nt_ * 16);
                const int kvb = kv0 + lg * 4;
                float v[4][4];
                #pragma unroll
                for (int mi = 0; mi < 4; ++mi)
                    #pragma unroll
                    for (int r = 0; r < 4; ++r) {
                        float x = s[mi][nt_][r];
                        if (!full) x = (kvb + mi * 16 + r <= qn) ? x : -INFINITY;
                        v[mi][r] = x;
                    }
                // tile max (16 local + xor16 + xor32)
                float mx0 = fmaxf(fmaxf(v[0][0], v[0][1]), fmaxf(v[0][2], v[0][3]));
                float mx1 = fmaxf(fmaxf(v[1][0], v[1][1]), fmaxf(v[1][2], v[1][3]));
                float mx2 = fmaxf(fmaxf(v[2][0], v[2][1]), fmaxf(v[2][2], v[2][3]));
                float mx3 = fmaxf(fmaxf(v[3][0], v[3][1]), fmaxf(v[3][2], v[3][3]));
                float pmax = fmaxf(fmaxf(mx0, mx1), fmaxf(mx2, mx3));
                pmax = fmaxf(pmax, __shfl_xor(pmax, 16));
                pmax = fmaxf(pmax, __shfl_xor(pmax, 32));

                const bool defer = __all(pmax <= mrow[nt_] + 8.0f);
                float mn;
                if (defer) {
                    mn = mrow[nt_];
                } else {
                    mn = fmaxf(mrow[nt_], pmax);
                    const float al = __expf(mrow[nt_] - mn);
                    lrow[nt_] *= al;
                    #pragma unroll
                    for (int di = 0; di < 4; ++di)
                        #pragma unroll
                        for (int r = 0; r < 4; ++r)
                            o[di][nt_][r] *= al;
                    mrow[nt_] = mn;
                }
                float p[4][4];
                #pragma unroll
                for (int mi = 0; mi < 4; ++mi)
                    #pragma unroll
                    for (int r = 0; r < 4; ++r)
                        p[mi][r] = __expf(v[mi][r] - mn);
                float rs = ((p[0][0] + p[0][1]) + (p[0][2] + p[0][3]))
                         + ((p[1][0] + p[1][1]) + (p[1][2] + p[1][3]))
                         + ((p[2][0] + p[2][1]) + (p[2][2] + p[2][3]))
                         + ((p[3][0] + p[3][1]) + (p[3][2] + p[3][3]));
                rs += __shfl_xor(rs, 16);
                rs += __shfl_xor(rs, 32);
                lrow[nt_] += rs;

                // pack P[q][kv] pairs -> LDS (wave-private, XOR-swizzled, b64 writes)
                const int rowoff = (nt_ * 16 + lr) * 128;
                const int xr = (lr & 7) << 4;
                #pragma unroll
                for (int mi = 0; mi < 4; ++mi) {
                    uint2 val;
                    val.x = cvtpk(p[mi][0], p[mi][1]);
                    val.y = cvtpk(p[mi][2], p[mi][3]);
                    *(uint2*)(pw + rowoff + ((32 * mi + 8 * lg) ^ xr)) = val;
                }
            }
            asm volatile("s_waitcnt lgkmcnt(0)" ::: "memory");
            __builtin_amdgcn_sched_barrier(0);

            // ---- PV: O^T[d][q] += V^T[d][kv] * P^T[kv][q] ----
            __builtin_amdgcn_s_setprio(1);
            #pragma unroll
            for (int ks = 0; ks < 2; ++ks) {
                bf16x8 pb[2];
                #pragma unroll
                for (int nt_ = 0; nt_ < 2; ++nt_) {
                    const int byteoff = (nt_ * 16 + lr) * 128 + (((64 * ks + 16 * lg)) ^ ((lr & 7) << 4));
                    pb[nt_] = *(const bf16x8*)(pw + byteoff);
                }
                #pragma unroll
                for (int di = 0; di < 4; ++di) {
                    bf16x8 vf = *(const bf16x8*)&Vl[buf][swz(di * 16 + lr, ks * 4 + lg)];
                    o[di][0] = __builtin_amdgcn_mfma_f32_16x16x32_bf16(vf, pb[0], o[di][0], 0, 0, 0);
                    o[di][1] = __builtin_amdgcn_mfma_f32_16x16x32_bf16(vf, pb[1], o[di][1], 0, 0, 0);
                }
            }
            __builtin_amdgcn_s_setprio(0);
        }
        if (have_next) WRITET(buf ^ 1);   // vmcnt wait lands here, hidden under compute
        __syncthreads();
    }
    #undef LOADT
    #undef WRITET

    // ---- epilogue: normalize, transpose O^T -> O via Pl, coalesced stores ----
    #pragma unroll
    for (int nt_ = 0; nt_ < 2; ++nt_) {
        const float inv = 1.0f / lrow[nt_];
        const int rowoff = (nt_ * 16 + lr) * 128;
        const int xr = (lr & 7) << 4;
        #pragma unroll
        for (int di = 0; di < 4; ++di) {
            uint2 val;
            val.x = cvtpk(o[di][nt_][0] * inv, o[di][nt_][1] * inv);
            val.y = cvtpk(o[di][nt_][2] * inv, o[di][nt_][3] * inv);
            *(uint2*)(pw + rowoff + ((32 * di + 8 * lg) ^ xr)) = val;
        }
    }
    asm volatile("s_waitcnt lgkmcnt(0)" ::: "memory");
    __builtin_amdgcn_sched_barrier(0);
    {
        const int row = lane >> 1;          // 0..31
        const int half = lane & 1;
        const int xr2 = (row & 7) << 4;
        ushort* og = O + (size_t)(b * 2048 + qw + row) * 1024 + h * 64 + half * 32;
        #pragma unroll
        for (int c = 0; c < 4; ++c) {
            uint4 val = *(const uint4*)(pw + row * 128 + ((half * 64 + c * 16) ^ xr2));
            *(uint4*)&og[c * 8] = val;
        }
    }
}

// ---------------- launch ----------------
extern "C" void kernel_launch(void* const* d_in, const int* in_sizes, int n_in,
                              void* d_out, int out_size, void* d_ws, size_t ws_size,
                              hipStream_t stream) {
    const float* x  = (const float*)d_in[0];
    const float* Wk = (const float*)d_in[1];
    const float* Wq = (const float*)d_in[2];
    const float* Wv = (const float*)d_in[3];
    const float* Wp = (const float*)d_in[4];
    const float* bp = (const float*)d_in[5];
    float* out = (float*)d_out;

    char* ws = (char*)d_ws;
    ushort* Xb   = (ushort*)(ws);                       // 8192x1024 bf16 = 16 MB
    ushort* Wcat = (ushort*)(ws + 16777216);            // 4096x1024 bf16 = 8 MB
    ushort* QKV  = (ushort*)(ws + 25165824);            // 8192x3072 bf16 = 48 MB
    ushort* Vt   = (ushort*)(ws + 75497472);            // 1024x8192 bf16 = 16 MB
    ushort* Obuf = (ushort*)(ws + 92274688);            // 8192x1024 bf16 = 16 MB

    cast_w_kernel<<<4096, 256, 0, stream>>>(Wq, Wk, Wv, Wp, Wcat);
    cast_x_kernel<<<8192, 256, 0, stream>>>(x, Xb);
    gemm_bt_kernel<true><<<1536, 256, 0, stream>>>(Xb, Wcat, QKV, nullptr, 8192, 3072, 1024, 24);
    transpose_v_kernel<<<dim3(256, 32), dim3(32, 8), 0, stream>>>(QKV, Vt);
    attn_kernel<<<dim3(64, 16), 256, 0, stream>>>(QKV, Vt, Obuf);
    gemm_bt_kernel<false><<<512, 256, 0, stream>>>(Obuf, Wcat + (size_t)3072 * 1024, out, bp, 8192, 1024, 1024, 8);
}